// Round 1
// baseline (19090.302 us; speedup 1.0000x reference)
//
#include <hip/hip_runtime.h>
#include <hip/hip_bf16.h>
#include <math.h>

#define SEQ 128
#define BATCH 32
#define EDIM 300
#define HDIM 1024
#define VOCAB 32000
#define MAXLEN 48

// ---------------- workspace layout (floats) ----------------
#define OFF_XS    0L                       // [S][B][E]      1,228,800
#define OFF_GI    1228800L                 // [S][B][3H]    12,582,912
#define OFF_YS0   13811712L                // [S][B][H]      4,194,304
#define OFF_HENC  18006016L                // [2][B][H]         65,536
#define OFF_HID   18071552L                // [2][B][H]         65,536
#define OFF_WXP   18137088L                // [3H][320]        983,040
#define OFF_EMB   19120128L                // [B][320]          10,240
#define OFF_PGH   19130368L                // [4][B][3][H]     393,216
#define OFF_PGI   19523584L                // [4][B][3][H]     393,216

// ---------------- embedding gather: xs[s][b][:] = fr_emb[fr[b][s]] ----------------
__global__ __launch_bounds__(256) void embed_fr_k(const int* __restrict__ fr,
                                                  const float* __restrict__ fr_emb,
                                                  float* __restrict__ xs)
{
    int idx = blockIdx.x * 256 + threadIdx.x;
    if (idx >= SEQ * BATCH * EDIM) return;
    int s = idx / (BATCH * EDIM);
    int r = idx - s * (BATCH * EDIM);
    int b = r / EDIM;
    int e = r - b * EDIM;
    int tokid = fr[b * SEQ + s];
    xs[(s * BATCH + b) * EDIM + e] = fr_emb[(long)tokid * EDIM + e];
}

// ---------------- zero-pad dec_Wih0 [3H][300] -> [3H][320] (dst pre-zeroed) -------
__global__ __launch_bounds__(256) void pad_w_k(const float* __restrict__ src,
                                               float* __restrict__ dst)
{
    int idx = blockIdx.x * 256 + threadIdx.x;
    if (idx >= 3 * HDIM * EDIM) return;
    int row = idx / EDIM;
    int k = idx - row * EDIM;
    dst[row * 320 + k] = src[row * EDIM + k];
}

// ---------------- BOS embedding into padded emb buffer ----------------
__global__ __launch_bounds__(256) void bos_k(const float* __restrict__ en_emb,
                                             float* __restrict__ emb_pad)
{
    int idx = blockIdx.x * 256 + threadIdx.x;
    if (idx >= BATCH * EDIM) return;
    int b = idx / EDIM;
    int e = idx - b * EDIM;
    emb_pad[b * 320 + e] = en_emb[1 * EDIM + e];   // EN_BOS = 1
}

// ---------------- generic fp32 GEMM: C[m][n] = A[m][k] dot B[n][k] + bias[n] -------
// tile: BM x 64, BK = 16, 256 threads (16x16), thread computes (BM/16) x 4
// M must be a multiple of BM; N a multiple of 64 (true for all our calls).
template<int BM>
__global__ __launch_bounds__(256) void gemm_nt(const float* __restrict__ A, int lda,
                                               const float* __restrict__ B, int ldb,
                                               const float* __restrict__ bias,
                                               float* __restrict__ C, long ldc,
                                               int K)
{
    __shared__ __align__(16) float As[BM * 17];
    __shared__ __align__(16) float Bs[16 * 68];
    const int tid = threadIdx.x;
    const int tx = tid & 15, ty = tid >> 4;
    const int n0 = blockIdx.x * 64;
    const int m0 = blockIdx.y * BM;
    constexpr int RM = BM / 16;
    float acc[RM][4];
    #pragma unroll
    for (int r = 0; r < RM; ++r)
        for (int c = 0; c < 4; ++c) acc[r][c] = 0.f;

    for (int k0 = 0; k0 < K; k0 += 16) {
        #pragma unroll
        for (int e = tid; e < BM * 16; e += 256) {
            int r = e >> 4, kk = e & 15;
            float v = 0.f;
            if (k0 + kk < K) v = A[(long)(m0 + r) * lda + k0 + kk];
            As[r * 17 + kk] = v;
        }
        #pragma unroll
        for (int e = tid; e < 64 * 16; e += 256) {
            int r = e >> 4, kk = e & 15;
            float v = 0.f;
            if (k0 + kk < K) v = B[(long)(n0 + r) * ldb + k0 + kk];
            Bs[kk * 68 + r] = v;       // transposed stage
        }
        __syncthreads();
        #pragma unroll
        for (int kk = 0; kk < 16; ++kk) {
            float4 bv = *(const float4*)&Bs[kk * 68 + tx * 4];
            #pragma unroll
            for (int r = 0; r < RM; ++r) {
                float av = As[(ty + r * 16) * 17 + kk];
                acc[r][0] += av * bv.x;
                acc[r][1] += av * bv.y;
                acc[r][2] += av * bv.z;
                acc[r][3] += av * bv.w;
            }
        }
        __syncthreads();
    }
    float4 bb = *(const float4*)&bias[n0 + tx * 4];
    #pragma unroll
    for (int r = 0; r < RM; ++r) {
        float4 o;
        o.x = acc[r][0] + bb.x; o.y = acc[r][1] + bb.y;
        o.z = acc[r][2] + bb.z; o.w = acc[r][3] + bb.w;
        *(float4*)&C[(long)(m0 + ty + r * 16) * ldc + n0 + tx * 4] = o;
    }
}

// ---------------- GRU partial-GEMM kernel ----------------
// 64 blocks = 4 K-splits x 16 i-tiles(64). 256 threads: ii = tid&63, bgroup = tid>>6.
// gh[b][g][i] partial over K/4 of H;  if HAS_X also gi over Kx/4.
// Writes Pgh/Pgi [ks][b][g][i].
template<bool HAS_X>
__global__ __launch_bounds__(256) void gru_part(const float* __restrict__ Whh,
                                                const float* __restrict__ hvec,
                                                const float* __restrict__ Wx, int ldwx,
                                                const float* __restrict__ xvec, int ldx, int Kx,
                                                float* __restrict__ Pgh,
                                                float* __restrict__ Pgi)
{
    __shared__ __align__(16) float ws_[192 * 20];
    __shared__ __align__(16) float hs_[32 * 20];
    const int tid = threadIdx.x;
    const int ii = tid & 63, bg = tid >> 6;
    const int it = blockIdx.x & 15, ks = blockIdx.x >> 4;
    const int i0 = it * 64;
    float acc[3][8];

    auto mac = [&](const float* __restrict__ W, int ldw,
                   const float* __restrict__ V, int ldv,
                   int kbeg, int ntiles) {
        #pragma unroll 1
        for (int t = 0; t < ntiles; ++t) {
            int k0 = kbeg + t * 16;
            #pragma unroll
            for (int f = 0; f < 3; ++f) {            // stage W: 192 rows x 16
                int e = tid + f * 256;               // 0..767 float4s
                int row = e >> 2, q = e & 3;
                int g = row >> 6, r = row & 63;
                float4 v = *(const float4*)&W[(long)(g * HDIM + i0 + r) * ldw + k0 + q * 4];
                *(float4*)&ws_[row * 20 + q * 4] = v;
            }
            if (tid < 128) {                         // stage V: 32 rows x 16
                int row = tid >> 2, q = tid & 3;
                float4 v = *(const float4*)&V[(long)row * ldv + k0 + q * 4];
                *(float4*)&hs_[row * 20 + q * 4] = v;
            }
            __syncthreads();
            #pragma unroll
            for (int k4 = 0; k4 < 4; ++k4) {
                float4 wr = *(const float4*)&ws_[(ii) * 20 + k4 * 4];
                float4 wz = *(const float4*)&ws_[(64 + ii) * 20 + k4 * 4];
                float4 wn = *(const float4*)&ws_[(128 + ii) * 20 + k4 * 4];
                #pragma unroll
                for (int bb = 0; bb < 8; ++bb) {
                    float4 hv = *(const float4*)&hs_[(bg * 8 + bb) * 20 + k4 * 4];
                    acc[0][bb] += wr.x * hv.x + wr.y * hv.y + wr.z * hv.z + wr.w * hv.w;
                    acc[1][bb] += wz.x * hv.x + wz.y * hv.y + wz.z * hv.z + wz.w * hv.w;
                    acc[2][bb] += wn.x * hv.x + wn.y * hv.y + wn.z * hv.z + wn.w * hv.w;
                }
            }
            __syncthreads();
        }
    };

    // hidden part: K = 1024, split into 4 x 256
    #pragma unroll
    for (int g = 0; g < 3; ++g)
        for (int bb = 0; bb < 8; ++bb) acc[g][bb] = 0.f;
    mac(Whh, HDIM, hvec, HDIM, ks * 256, 16);
    #pragma unroll
    for (int g = 0; g < 3; ++g)
        #pragma unroll
        for (int bb = 0; bb < 8; ++bb)
            Pgh[((long)(ks * 32 + bg * 8 + bb) * 3 + g) * HDIM + i0 + ii] = acc[g][bb];

    if (HAS_X) {
        int kq = Kx >> 2;                 // per-split K range
        #pragma unroll
        for (int g = 0; g < 3; ++g)
            for (int bb = 0; bb < 8; ++bb) acc[g][bb] = 0.f;
        mac(Wx, ldwx, xvec, ldx, ks * kq, kq >> 4);
        #pragma unroll
        for (int g = 0; g < 3; ++g)
            #pragma unroll
            for (int bb = 0; bb < 8; ++bb)
                Pgi[((long)(ks * 32 + bg * 8 + bb) * 3 + g) * HDIM + i0 + ii] = acc[g][bb];
    }
}

// ---------------- GRU gate/update kernel ----------------
// 128 blocks x 256 = 32768 threads = B x H.
// GI_PARTIAL: gi from Pgi partials + bih.  else: gi directly from Gi (bias included).
template<bool GI_PARTIAL>
__global__ __launch_bounds__(256) void gru_gates(const float* __restrict__ Pgh,
                                                 const float* __restrict__ Pgi,
                                                 const float* __restrict__ Gi,
                                                 const float* __restrict__ bih,
                                                 const float* __restrict__ bhh,
                                                 const float* __restrict__ h_in,
                                                 float* __restrict__ h_out,
                                                 float* __restrict__ ys)
{
    int idx = blockIdx.x * 256 + threadIdx.x;
    int b = idx >> 10, i = idx & 1023;
    float gh[3], gi[3];
    #pragma unroll
    for (int g = 0; g < 3; ++g) {
        float a = bhh[g * HDIM + i];
        #pragma unroll
        for (int ks = 0; ks < 4; ++ks)
            a += Pgh[((long)(ks * 32 + b) * 3 + g) * HDIM + i];
        gh[g] = a;
        if (GI_PARTIAL) {
            float c = bih[g * HDIM + i];
            #pragma unroll
            for (int ks = 0; ks < 4; ++ks)
                c += Pgi[((long)(ks * 32 + b) * 3 + g) * HDIM + i];
            gi[g] = c;
        } else {
            gi[g] = Gi[b * (3 * HDIM) + g * HDIM + i];
        }
    }
    float r = 1.f / (1.f + expf(-(gi[0] + gh[0])));
    float z = 1.f / (1.f + expf(-(gi[1] + gh[1])));
    float n = tanhf(gi[2] + r * gh[2]);
    float h = h_in[b * HDIM + i];
    float hn = (1.f - z) * n + z * h;
    h_out[b * HDIM + i] = hn;
    if (ys) ys[b * HDIM + i] = hn;
}

// ---------------- argmax (numpy first-index tiebreak) + next-embedding gather -----
__global__ __launch_bounds__(256) void argmax_embed_k(const float* __restrict__ logits,
                                                      long ldl,
                                                      const float* __restrict__ en_emb,
                                                      float* __restrict__ emb_pad)
{
    int b = blockIdx.x;
    const float* row = logits + (long)b * ldl;
    int tid = threadIdx.x;
    float best = -INFINITY;
    int bi = VOCAB;
    for (int v = tid; v < VOCAB; v += 256) {
        float x = row[v];
        if (x > best) { best = x; bi = v; }     // ascending v -> keeps first occurrence
    }
    __shared__ float sv[256];
    __shared__ int si[256];
    sv[tid] = best; si[tid] = bi;
    __syncthreads();
    for (int s = 128; s > 0; s >>= 1) {
        if (tid < s) {
            float o = sv[tid + s]; int oi = si[tid + s];
            if (o > sv[tid] || (o == sv[tid] && oi < si[tid])) { sv[tid] = o; si[tid] = oi; }
        }
        __syncthreads();
    }
    int tok = si[0];
    for (int e = tid; e < EDIM; e += 256)
        emb_pad[b * 320 + e] = en_emb[(long)tok * EDIM + e];
}

// ---------------- host-side orchestration ----------------
extern "C" void kernel_launch(void* const* d_in, const int* in_sizes, int n_in,
                              void* d_out, int out_size, void* d_ws, size_t ws_size,
                              hipStream_t stream)
{
    const int*   fr      = (const int*)  d_in[0];
    const float* fr_emb  = (const float*)d_in[1];
    const float* en_emb  = (const float*)d_in[2];
    const float* eWih0   = (const float*)d_in[3];
    const float* eWhh0   = (const float*)d_in[4];
    const float* ebih0   = (const float*)d_in[5];
    const float* ebhh0   = (const float*)d_in[6];
    const float* eWih1   = (const float*)d_in[7];
    const float* eWhh1   = (const float*)d_in[8];
    const float* ebih1   = (const float*)d_in[9];
    const float* ebhh1   = (const float*)d_in[10];
    const float* tW      = (const float*)d_in[11];
    const float* tb      = (const float*)d_in[12];
    const float* dWih0   = (const float*)d_in[13];
    const float* dWhh0   = (const float*)d_in[14];
    const float* dbih0   = (const float*)d_in[15];
    const float* dbhh0   = (const float*)d_in[16];
    const float* dWih1   = (const float*)d_in[17];
    const float* dWhh1   = (const float*)d_in[18];
    const float* dbih1   = (const float*)d_in[19];
    const float* dbhh1   = (const float*)d_in[20];
    const float* vW      = (const float*)d_in[21];
    const float* vb      = (const float*)d_in[22];
    float* out = (float*)d_out;
    float* w   = (float*)d_ws;

    float* xs     = w + OFF_XS;
    float* Gi     = w + OFF_GI;
    float* ys0    = w + OFF_YS0;
    float* henc0  = w + OFF_HENC;
    float* henc1  = henc0 + BATCH * HDIM;
    float* hid0   = w + OFF_HID;
    float* hid1   = hid0 + BATCH * HDIM;
    float* WxPad  = w + OFF_WXP;
    float* embp   = w + OFF_EMB;
    float* Pgh    = w + OFF_PGH;
    float* Pgi    = w + OFF_PGI;

    // zero-init state & padded buffers (ws is re-poisoned before every launch)
    hipMemsetAsync(henc0, 0, 2 * BATCH * HDIM * sizeof(float), stream);
    hipMemsetAsync(WxPad, 0, 3 * HDIM * 320 * sizeof(float), stream);
    hipMemsetAsync(embp,  0, BATCH * 320 * sizeof(float), stream);

    // embeddings + batched encoder input projections
    embed_fr_k<<<(SEQ * BATCH * EDIM + 255) / 256, 256, 0, stream>>>(fr, fr_emb, xs);
    gemm_nt<64><<<dim3(48, 64), 256, 0, stream>>>(xs, EDIM, eWih0, EDIM, ebih0,
                                                  Gi, 3 * HDIM, EDIM);

    // ---- encoder layer 0 ----
    for (int s = 0; s < SEQ; ++s) {
        gru_part<false><<<64, 256, 0, stream>>>(eWhh0, henc0, nullptr, 0, nullptr, 0, 0,
                                                Pgh, nullptr);
        gru_gates<false><<<128, 256, 0, stream>>>(Pgh, nullptr,
                                                  Gi + (long)s * BATCH * 3 * HDIM,
                                                  nullptr, ebhh0, henc0, henc0,
                                                  ys0 + (long)s * BATCH * HDIM);
    }
    // ---- encoder layer 1 ----
    gemm_nt<64><<<dim3(48, 64), 256, 0, stream>>>(ys0, HDIM, eWih1, HDIM, ebih1,
                                                  Gi, 3 * HDIM, HDIM);
    for (int s = 0; s < SEQ; ++s) {
        gru_part<false><<<64, 256, 0, stream>>>(eWhh1, henc1, nullptr, 0, nullptr, 0, 0,
                                                Pgh, nullptr);
        gru_gates<false><<<128, 256, 0, stream>>>(Pgh, nullptr,
                                                  Gi + (long)s * BATCH * 3 * HDIM,
                                                  nullptr, ebhh1, henc1, henc1, nullptr);
    }
    // ---- hidden transform: [2*B, H] @ trans_W^T + trans_b -> decoder init states ----
    gemm_nt<64><<<dim3(16, 1), 256, 0, stream>>>(henc0, HDIM, tW, HDIM, tb,
                                                 hid0, HDIM, HDIM);

    // ---- decoder prep ----
    pad_w_k<<<(3 * HDIM * EDIM + 255) / 256, 256, 0, stream>>>(dWih0, WxPad);
    bos_k<<<(BATCH * EDIM + 255) / 256, 256, 0, stream>>>(en_emb, embp);

    // ---- autoregressive decoder ----
    for (int t = 0; t < MAXLEN; ++t) {
        float* lt = out + (long)t * VOCAB;          // logits row block for step t
        gru_part<true><<<64, 256, 0, stream>>>(dWhh0, hid0, WxPad, 320, embp, 320, 320,
                                               Pgh, Pgi);
        gru_gates<true><<<128, 256, 0, stream>>>(Pgh, Pgi, nullptr, dbih0, dbhh0,
                                                 hid0, hid0, nullptr);
        gru_part<true><<<64, 256, 0, stream>>>(dWhh1, hid1, dWih1, HDIM, hid0, HDIM, HDIM,
                                               Pgh, Pgi);
        gru_gates<true><<<128, 256, 0, stream>>>(Pgh, Pgi, nullptr, dbih1, dbhh1,
                                                 hid1, hid1, nullptr);
        // logits[b][v] -> out[b][t][v]  (row stride MAXLEN*VOCAB)
        gemm_nt<32><<<dim3(VOCAB / 64, 1), 256, 0, stream>>>(hid1, HDIM, vW, HDIM, vb,
                                                             lt, (long)MAXLEN * VOCAB, HDIM);
        argmax_embed_k<<<BATCH, 256, 0, stream>>>(lt, (long)MAXLEN * VOCAB, en_emb, embp);
    }
}